// Round 1
// baseline (918.390 us; speedup 1.0000x reference)
//
#include <hip/hip_runtime.h>

// GPT2 attention forward, MI355X bf16-MFMA implementation.
// Outputs (fp32, concatenated): attn_output [2,2048,1024], attn_weights [2,16,2048,2048],
// k [2,16,2048,64], v [2,16,2048,64].

typedef __attribute__((ext_vector_type(8))) short bf8_t;   // 8 x bf16 (4 VGPRs)
typedef __attribute__((ext_vector_type(4))) float f4_t;    // 4 x f32

#define MFMA(a, b, c) __builtin_amdgcn_mfma_f32_16x16x32_bf16(a, b, c, 0, 0, 0)

static __device__ __forceinline__ unsigned short f2bf(float f) {
    union { float f; unsigned u; } x; x.f = f;
    unsigned u = x.u;
    return (unsigned short)((u + 0x7fffu + ((u >> 16) & 1u)) >> 16);
}

#define NE 4194304ULL          // B*S*D = 2*2048*1024
#define AW 134217728ULL        // B*H*S*S

// ---------------- prep kernels ----------------

__global__ void cast_hidden(const float* __restrict__ src, unsigned short* __restrict__ dst) {
    int i = (blockIdx.x * 256 + threadIdx.x) * 4;
    float4 h = *(const float4*)(src + i);
    ushort4 o;
    o.x = f2bf(h.x); o.y = f2bf(h.y); o.z = f2bf(h.z); o.w = f2bf(h.w);
    *(ushort4*)(dst + i) = o;
}

// W [1024][1024] f32 -> W^T [1024][1024] bf16 (row n, contiguous k)
__global__ void transpose_w(const float* __restrict__ wq, const float* __restrict__ wk,
                            const float* __restrict__ wv, const float* __restrict__ wc,
                            unsigned short* __restrict__ wqkvT, unsigned short* __restrict__ wcT) {
    __shared__ float tile[32][33];
    int z = blockIdx.z;
    const float* W = z == 0 ? wq : z == 1 ? wk : z == 2 ? wv : wc;
    unsigned short* dst = (z < 3) ? (wqkvT + (size_t)z * 1024 * 1024) : wcT;
    int x0 = blockIdx.x * 32, y0 = blockIdx.y * 32;
    int tx = threadIdx.x, ty = threadIdx.y;   // block (32,8)
#pragma unroll
    for (int i = 0; i < 4; ++i)
        tile[ty + i * 8][tx] = W[(size_t)(y0 + ty + i * 8) * 1024 + x0 + tx];
    __syncthreads();
#pragma unroll
    for (int i = 0; i < 4; ++i)
        dst[(size_t)(x0 + ty + i * 8) * 1024 + y0 + tx] = f2bf(tile[tx][ty + i * 8]);
}

// ---------------- QKV fused GEMM ----------------
// A [4096][1024] bf16 (hidden), BT [3072][1024] bf16 (wq|wk|wv transposed).
// Epilogue scatters into head layouts; q pre-scaled by 0.125 (exact).
__global__ __launch_bounds__(256) void gemm_qkv(
    const unsigned short* __restrict__ A, const unsigned short* __restrict__ BT,
    const float* __restrict__ bq, const float* __restrict__ bk, const float* __restrict__ bv,
    unsigned short* __restrict__ q_bf, unsigned short* __restrict__ k_bf,
    unsigned short* __restrict__ vT_bf, float* __restrict__ out_k, float* __restrict__ out_v)
{
    __shared__ __align__(16) unsigned short As[128 * 40];  // pad 32->40: 2-way max bank alias
    __shared__ __align__(16) unsigned short Bs[128 * 40];
    const int m0 = blockIdx.y * 128, n0 = blockIdx.x * 128;
    const int tid = threadIdx.x, w = tid >> 6, lane = tid & 63, ln = lane & 15, quad = lane >> 4;
    const int wm = (w & 1) * 64, wn = (w >> 1) * 64;
    f4_t acc[4][4] = {};

    for (int kb = 0; kb < 1024; kb += 32) {
        __syncthreads();
#pragma unroll
        for (int p = 0; p < 2; ++p) {
            int c = tid + p * 256;
            int r = c >> 2, col = (c & 3) * 8;
            *(uint4*)&As[r * 40 + col] = *(const uint4*)&A[(size_t)(m0 + r) * 1024 + kb + col];
            *(uint4*)&Bs[r * 40 + col] = *(const uint4*)&BT[(size_t)(n0 + r) * 1024 + kb + col];
        }
        __syncthreads();
        bf8_t af[4], bfr[4];
#pragma unroll
        for (int i = 0; i < 4; ++i) af[i] = *(const bf8_t*)&As[(wm + i * 16 + ln) * 40 + quad * 8];
#pragma unroll
        for (int j = 0; j < 4; ++j) bfr[j] = *(const bf8_t*)&Bs[(wn + j * 16 + ln) * 40 + quad * 8];
#pragma unroll
        for (int i = 0; i < 4; ++i)
#pragma unroll
            for (int j = 0; j < 4; ++j)
                acc[i][j] = MFMA(af[i], bfr[j], acc[i][j]);
    }
#pragma unroll
    for (int j = 0; j < 4; ++j) {
        int coln = n0 + wn + j * 16 + ln;                 // 0..3071
        int which = coln >> 10, d = coln & 1023, h = d >> 6, e = d & 63;
        float bias = which == 0 ? bq[d] : (which == 1 ? bk[d] : bv[d]);
#pragma unroll
        for (int i = 0; i < 4; ++i) {
#pragma unroll
            for (int v = 0; v < 4; ++v) {
                int row = m0 + wm + i * 16 + quad * 4 + v;  // 0..4095
                int b = row >> 11, s = row & 2047;
                float val = acc[i][j][v] + bias;
                size_t hidx = (((size_t)(b * 16 + h)) * 2048 + s) * 64 + e;
                if (which == 0) {
                    q_bf[hidx] = f2bf(val * 0.125f);
                } else if (which == 1) {
                    k_bf[hidx] = f2bf(val);
                    out_k[hidx] = val;
                } else {
                    vT_bf[((size_t)(b * 16 + h) * 64 + e) * 2048 + s] = f2bf(val);
                    out_v[hidx] = val;
                }
            }
        }
    }
}

// ---------------- fused causal attention ----------------
// Block: (bh, qtile of 64 rows). 4 waves x 16-row strips, each wave independent.
// Pass 1: l = sum_k exp(q.k) (no max-subtract: scores ~N(0,0.4), safe in fp32;
// masked -> exp(-inf)=0 matches reference exactly since exp(-10000-m) underflows).
// Pass 2: recompute Sc, write P to attn_weights (zeros above diagonal), PV via
// LDS round-trip for the C->A layout transform.
__global__ __launch_bounds__(256) void attn_fused(
    const unsigned short* __restrict__ q_bf,   // [32][2048][64], pre-scaled
    const unsigned short* __restrict__ k_bf,   // [32][2048][64]
    const unsigned short* __restrict__ vT_bf,  // [32][64][2048]
    float* __restrict__ attn_w,                // [32][2048][2048]
    unsigned short* __restrict__ attnpre)      // [4096][1024] bf16
{
    __shared__ __align__(16) unsigned short Qlds[64 * 72];   // pad 64->72
    __shared__ __align__(16) unsigned short Plds[4][16 * 40];
    const int bh = blockIdx.x, qt = blockIdx.y, q0 = qt * 64;
    const int tid = threadIdx.x, w = tid >> 6, lane = tid & 63, ln = lane & 15, quad = lane >> 4;
#pragma unroll
    for (int p = 0; p < 2; ++p) {
        int c = tid + p * 256;
        int r = c >> 3, e0 = (c & 7) * 8;
        *(uint4*)&Qlds[r * 72 + e0] = *(const uint4*)&q_bf[((size_t)bh * 2048 + q0 + r) * 64 + e0];
    }
    __syncthreads();
    const int r0 = w * 16;
    const int growbase = q0 + r0;
    const int rmax = growbase + 15;
    bf8_t af0 = *(const bf8_t*)&Qlds[(r0 + ln) * 72 + quad * 8];
    bf8_t af1 = *(const bf8_t*)&Qlds[(r0 + ln) * 72 + 32 + quad * 8];
    const unsigned short* kb_base = k_bf + (size_t)bh * 2048 * 64;

    // pass 1
    f4_t lsum = {0.f, 0.f, 0.f, 0.f};
    const int nkt = (rmax >> 4) + 1;
    for (int kt = 0; kt < nkt; ++kt) {
        int col0 = kt * 16;
        const unsigned short* kp = kb_base + (size_t)(col0 + ln) * 64 + quad * 8;
        bf8_t b0 = *(const bf8_t*)kp;
        bf8_t b1 = *(const bf8_t*)(kp + 32);
        f4_t sc = {0.f, 0.f, 0.f, 0.f};
        sc = MFMA(af0, b0, sc);
        sc = MFMA(af1, b1, sc);
        int col = col0 + ln;
#pragma unroll
        for (int v = 0; v < 4; ++v) {
            int row = growbase + quad * 4 + v;
            if (col <= row) lsum[v] += __expf(sc[v]);
        }
    }
#pragma unroll
    for (int m = 1; m < 16; m <<= 1) {
#pragma unroll
        for (int v = 0; v < 4; ++v) lsum[v] += __shfl_xor(lsum[v], m);
    }
    float linv[4];
#pragma unroll
    for (int v = 0; v < 4; ++v) linv[v] = 1.f / lsum[v];

    // pass 2
    f4_t oacc[4] = {};
    float* awp = attn_w + (size_t)bh * 2048 * 2048;
    const unsigned short* vt_base = vT_bf + (size_t)bh * 64 * 2048;
    for (int kc = 0; kc < 64; ++kc) {
        int cbase = kc * 32;
        bool needed = (cbase <= rmax);
#pragma unroll
        for (int sub = 0; sub < 2; ++sub) {
            int col0 = cbase + sub * 16;
            int col = col0 + ln;
            f4_t p = {0.f, 0.f, 0.f, 0.f};
            if (col0 <= rmax) {
                const unsigned short* kp = kb_base + (size_t)(col0 + ln) * 64 + quad * 8;
                bf8_t b0 = *(const bf8_t*)kp;
                bf8_t b1 = *(const bf8_t*)(kp + 32);
                f4_t sc = {0.f, 0.f, 0.f, 0.f};
                sc = MFMA(af0, b0, sc);
                sc = MFMA(af1, b1, sc);
#pragma unroll
                for (int v = 0; v < 4; ++v) {
                    int row = growbase + quad * 4 + v;
                    p[v] = (col <= row) ? __expf(sc[v]) * linv[v] : 0.f;
                }
            }
#pragma unroll
            for (int v = 0; v < 4; ++v) {
                awp[(size_t)(growbase + quad * 4 + v) * 2048 + col] = p[v];
                Plds[w][(quad * 4 + v) * 40 + sub * 16 + ln] = f2bf(p[v]);
            }
        }
        if (needed) {
            bf8_t pf = *(const bf8_t*)&Plds[w][ln * 40 + quad * 8];
#pragma unroll
            for (int j = 0; j < 4; ++j) {
                const unsigned short* vp = vt_base + (size_t)(j * 16 + ln) * 2048 + cbase + quad * 8;
                bf8_t vb = *(const bf8_t*)vp;
                oacc[j] = MFMA(pf, vb, oacc[j]);
            }
        }
    }
    int b = bh >> 4, h = bh & 15;
#pragma unroll
    for (int j = 0; j < 4; ++j) {
#pragma unroll
        for (int v = 0; v < 4; ++v) {
            int s = growbase + quad * 4 + v;
            int e = j * 16 + ln;
            attnpre[(size_t)(b * 2048 + s) * 1024 + h * 64 + e] = f2bf(oacc[j][v]);
        }
    }
}

// ---------------- c_proj GEMM ----------------
__global__ __launch_bounds__(256) void gemm_cproj(
    const unsigned short* __restrict__ A,    // [4096][1024] bf16 attnpre
    const unsigned short* __restrict__ BT,   // [1024][1024] bf16 wc^T
    const float* __restrict__ bc, float* __restrict__ out)
{
    __shared__ __align__(16) unsigned short As[128 * 40];
    __shared__ __align__(16) unsigned short Bs[128 * 40];
    const int m0 = blockIdx.y * 128, n0 = blockIdx.x * 128;
    const int tid = threadIdx.x, w = tid >> 6, lane = tid & 63, ln = lane & 15, quad = lane >> 4;
    const int wm = (w & 1) * 64, wn = (w >> 1) * 64;
    f4_t acc[4][4] = {};

    for (int kb = 0; kb < 1024; kb += 32) {
        __syncthreads();
#pragma unroll
        for (int p = 0; p < 2; ++p) {
            int c = tid + p * 256;
            int r = c >> 2, col = (c & 3) * 8;
            *(uint4*)&As[r * 40 + col] = *(const uint4*)&A[(size_t)(m0 + r) * 1024 + kb + col];
            *(uint4*)&Bs[r * 40 + col] = *(const uint4*)&BT[(size_t)(n0 + r) * 1024 + kb + col];
        }
        __syncthreads();
        bf8_t af[4], bfr[4];
#pragma unroll
        for (int i = 0; i < 4; ++i) af[i] = *(const bf8_t*)&As[(wm + i * 16 + ln) * 40 + quad * 8];
#pragma unroll
        for (int j = 0; j < 4; ++j) bfr[j] = *(const bf8_t*)&Bs[(wn + j * 16 + ln) * 40 + quad * 8];
#pragma unroll
        for (int i = 0; i < 4; ++i)
#pragma unroll
            for (int j = 0; j < 4; ++j)
                acc[i][j] = MFMA(af[i], bfr[j], acc[i][j]);
    }
#pragma unroll
    for (int j = 0; j < 4; ++j) {
        int coln = n0 + wn + j * 16 + ln;
        float bias = bc[coln];
#pragma unroll
        for (int i = 0; i < 4; ++i) {
#pragma unroll
            for (int v = 0; v < 4; ++v) {
                int row = m0 + wm + i * 16 + quad * 4 + v;
                out[(size_t)row * 1024 + coln] = acc[i][j][v] + bias;
            }
        }
    }
}

// ---------------- launch ----------------
extern "C" void kernel_launch(void* const* d_in, const int* in_sizes, int n_in,
                              void* d_out, int out_size, void* d_ws, size_t ws_size,
                              hipStream_t stream)
{
    const float* hs = (const float*)d_in[0];
    const float* wq = (const float*)d_in[1];
    const float* bq = (const float*)d_in[2];
    const float* wk = (const float*)d_in[3];
    const float* bk = (const float*)d_in[4];
    const float* wv = (const float*)d_in[5];
    const float* bv = (const float*)d_in[6];
    const float* wc = (const float*)d_in[7];
    const float* bc = (const float*)d_in[8];

    float* out      = (float*)d_out;
    float* out_aw   = out + NE;
    float* out_k    = out_aw + AW;
    float* out_v    = out_k + NE;

    char* ws = (char*)d_ws;
    unsigned short* hid_bf  = (unsigned short*)(ws);                // 8 MB
    unsigned short* wqkvT   = (unsigned short*)(ws + 8388608);      // 6 MB
    unsigned short* wcT     = (unsigned short*)(ws + 14680064);     // 2 MB
    unsigned short* q_bf    = (unsigned short*)(ws + 16777216);     // 8 MB
    unsigned short* k_bf    = (unsigned short*)(ws + 25165824);     // 8 MB
    unsigned short* vT_bf   = (unsigned short*)(ws + 33554432);     // 8 MB
    unsigned short* attnpre = (unsigned short*)(ws + 41943040);     // 8 MB

    cast_hidden<<<4096, 256, 0, stream>>>(hs, hid_bf);
    transpose_w<<<dim3(32, 32, 4), dim3(32, 8), 0, stream>>>(wq, wk, wv, wc, wqkvT, wcT);
    gemm_qkv<<<dim3(24, 32), 256, 0, stream>>>(hid_bf, wqkvT, bq, bk, bv,
                                               q_bf, k_bf, vT_bf, out_k, out_v);
    attn_fused<<<dim3(32, 32), 256, 0, stream>>>(q_bf, k_bf, vT_bf, out_aw, attnpre);
    gemm_cproj<<<dim3(8, 32), 256, 0, stream>>>(attnpre, wcT, bc, out);
}

// Round 2
// 810.433 us; speedup vs baseline: 1.1332x; 1.1332x over previous
//
#include <hip/hip_runtime.h>

// GPT2 attention forward, MI355X bf16-MFMA implementation.
// Outputs (fp32, concat): attn_output [2,2048,1024], attn_weights [2,16,2048,2048],
// k [2,16,2048,64], v [2,16,2048,64].

typedef __attribute__((ext_vector_type(8))) short bf8_t;   // 8 x bf16 (4 VGPRs)
typedef __attribute__((ext_vector_type(4))) float f4_t;    // 4 x f32

#define MFMA(a, b, c) __builtin_amdgcn_mfma_f32_16x16x32_bf16(a, b, c, 0, 0, 0)

static __device__ __forceinline__ unsigned short f2bf(float f) {
    union { float f; unsigned u; } x; x.f = f;
    unsigned u = x.u;
    return (unsigned short)((u + 0x7fffu + ((u >> 16) & 1u)) >> 16);
}

// async global->LDS, 16B per lane. LDS dest is wave-uniform base + lane*16.
static __device__ __forceinline__ void stage16(const unsigned short* g, unsigned short* lbase) {
    __builtin_amdgcn_global_load_lds(
        (const __attribute__((address_space(1))) unsigned int*)g,
        (__attribute__((address_space(3))) unsigned int*)lbase, 16, 0, 0);
}

#define NE 4194304ULL
#define AW 134217728ULL

// ---------------- prep kernels ----------------

__global__ void cast_hidden(const float* __restrict__ src, unsigned short* __restrict__ dst) {
    int i = (blockIdx.x * 256 + threadIdx.x) * 4;
    float4 h = *(const float4*)(src + i);
    ushort4 o;
    o.x = f2bf(h.x); o.y = f2bf(h.y); o.z = f2bf(h.z); o.w = f2bf(h.w);
    *(ushort4*)(dst + i) = o;
}

__global__ void transpose_w(const float* __restrict__ wq, const float* __restrict__ wk,
                            const float* __restrict__ wv, const float* __restrict__ wc,
                            unsigned short* __restrict__ wqkvT, unsigned short* __restrict__ wcT) {
    __shared__ float tile[32][33];
    int z = blockIdx.z;
    const float* W = z == 0 ? wq : z == 1 ? wk : z == 2 ? wv : wc;
    unsigned short* dst = (z < 3) ? (wqkvT + (size_t)z * 1024 * 1024) : wcT;
    int x0 = blockIdx.x * 32, y0 = blockIdx.y * 32;
    int tx = threadIdx.x, ty = threadIdx.y;
#pragma unroll
    for (int i = 0; i < 4; ++i)
        tile[ty + i * 8][tx] = W[(size_t)(y0 + ty + i * 8) * 1024 + x0 + tx];
    __syncthreads();
#pragma unroll
    for (int i = 0; i < 4; ++i)
        dst[(size_t)(x0 + ty + i * 8) * 1024 + y0 + tx] = f2bf(tile[tx][ty + i * 8]);
}

// ---------------- GEMM core (m97-style: global_load_lds + BK=64 + XOR swizzle) ------------
// Tile 128x128, BK=64. LDS tile [128][64] bf16 unpadded; 16B chunk (row,c') holds global
// chunk c = c' ^ (row&7). Fragment reads then land 2 lanes/bank (free).

#define GEMM_CORE(A_, B_, KDIM)                                                             \
    const int m0 = blockIdx.y * 128, n0 = blockIdx.x * 128;                                 \
    const int tid = threadIdx.x, w = tid >> 6, lane = tid & 63, ln = lane & 15,             \
              quad = lane >> 4;                                                             \
    const int wm = (w & 1) * 64, wn = (w >> 1) * 64;                                        \
    f4_t acc[4][4] = {};                                                                    \
    for (int kb = 0; kb < (KDIM); kb += 64) {                                               \
        __syncthreads();                                                                    \
        _Pragma("unroll")                                                                   \
        for (int p = 0; p < 4; ++p) {                                                       \
            int t = (w * 4 + p) * 64 + lane;                                                \
            int r = t >> 3, c = (t & 7) ^ (r & 7);                                          \
            stage16(&(A_)[(size_t)(m0 + r) * (KDIM) + kb + c * 8], &As[(w * 4 + p) * 512]); \
            stage16(&(B_)[(size_t)(n0 + r) * (KDIM) + kb + c * 8], &Bs[(w * 4 + p) * 512]); \
        }                                                                                   \
        __syncthreads();                                                                    \
        bf8_t af[2][4], bfm[2][4];                                                          \
        _Pragma("unroll")                                                                   \
        for (int h = 0; h < 2; ++h) {                                                       \
            _Pragma("unroll")                                                               \
            for (int i = 0; i < 4; ++i) {                                                   \
                int c = (h * 4 + quad) ^ (ln & 7);                                          \
                af[h][i] = *(const bf8_t*)&As[(wm + i * 16 + ln) * 64 + c * 8];             \
                bfm[h][i] = *(const bf8_t*)&Bs[(wn + i * 16 + ln) * 64 + c * 8];            \
            }                                                                               \
        }                                                                                   \
        _Pragma("unroll")                                                                   \
        for (int h = 0; h < 2; ++h)                                                         \
            _Pragma("unroll")                                                               \
            for (int i = 0; i < 4; ++i)                                                     \
                _Pragma("unroll")                                                           \
                for (int j = 0; j < 4; ++j)                                                 \
                    acc[i][j] = MFMA(af[h][i], bfm[h][j], acc[i][j]);                       \
    }

__global__ __launch_bounds__(256) void gemm_qkv(
    const unsigned short* __restrict__ A, const unsigned short* __restrict__ BT,
    const float* __restrict__ bq, const float* __restrict__ bk, const float* __restrict__ bv,
    unsigned short* __restrict__ q_bf, unsigned short* __restrict__ k_bf,
    unsigned short* __restrict__ vT_bf, float* __restrict__ out_k, float* __restrict__ out_v)
{
    __shared__ __align__(16) unsigned short As[128 * 64];
    __shared__ __align__(16) unsigned short Bs[128 * 64];
    GEMM_CORE(A, BT, 1024)
#pragma unroll
    for (int j = 0; j < 4; ++j) {
        int coln = n0 + wn + j * 16 + ln;                 // 0..3071
        int which = coln >> 10, d = coln & 1023, h = d >> 6, e = d & 63;
        float bias = which == 0 ? bq[d] : (which == 1 ? bk[d] : bv[d]);
#pragma unroll
        for (int i = 0; i < 4; ++i) {
#pragma unroll
            for (int v = 0; v < 4; ++v) {
                int row = m0 + wm + i * 16 + quad * 4 + v;
                int b = row >> 11, s = row & 2047;
                float val = acc[i][j][v] + bias;
                size_t hidx = (((size_t)(b * 16 + h)) * 2048 + s) * 64 + e;
                if (which == 0) {
                    q_bf[hidx] = f2bf(val * 0.125f);
                } else if (which == 1) {
                    k_bf[hidx] = f2bf(val);
                    out_k[hidx] = val;
                } else {
                    vT_bf[((size_t)(b * 16 + h) * 64 + e) * 2048 + s] = f2bf(val);
                    out_v[hidx] = val;
                }
            }
        }
    }
}

__global__ __launch_bounds__(256) void gemm_cproj(
    const unsigned short* __restrict__ A, const unsigned short* __restrict__ BT,
    const float* __restrict__ bc, float* __restrict__ out)
{
    __shared__ __align__(16) unsigned short As[128 * 64];
    __shared__ __align__(16) unsigned short Bs[128 * 64];
    GEMM_CORE(A, BT, 1024)
#pragma unroll
    for (int j = 0; j < 4; ++j) {
        int coln = n0 + wn + j * 16 + ln;
        float bias = bc[coln];
#pragma unroll
        for (int i = 0; i < 4; ++i) {
#pragma unroll
            for (int v = 0; v < 4; ++v) {
                int row = m0 + wm + i * 16 + quad * 4 + v;
                out[(size_t)row * 1024 + coln] = acc[i][j][v] + bias;
            }
        }
    }
}

// ---------------- fused causal attention ----------------
// Block: 128 q rows (bh, qt). Wave w owns strips {w*16, 64+w*16}. K/V fragments shared
// across both strips. Pass 1: row sums l (no max-subtract: scores ~N(0,0.4), fp32-safe;
// masked terms are exact 0 as in reference since exp(-10000+s) underflows bf16 threshold).
// Pass 2: recompute Sc, P -> per-wave f32 LDS -> float4 stores (128B rows), PV via MFMA.
__global__ __launch_bounds__(256) void attn_fused(
    const unsigned short* __restrict__ q_bf,   // [32][2048][64], pre-scaled by 0.125
    const unsigned short* __restrict__ k_bf,   // [32][2048][64]
    const unsigned short* __restrict__ vT_bf,  // [32][64][2048]
    float* __restrict__ attn_w,                // [32][2048][2048]
    unsigned short* __restrict__ attnpre)      // [4096][1024] bf16
{
    __shared__ __align__(16) unsigned short Qlds[128 * 72];   // 18 KB
    __shared__ __align__(16) float Pf32[4][16 * 36];          // 9 KB, per-wave scratch
    const int bh = blockIdx.x;
    const int q0 = (15 - blockIdx.y) * 128;     // biggest q-tiles dispatched first
    const int tid = threadIdx.x, w = tid >> 6, lane = tid & 63, ln = lane & 15, quad = lane >> 4;
#pragma unroll
    for (int p = 0; p < 4; ++p) {
        int c = tid + p * 256;                  // 0..1023
        int r = c >> 3, e0 = (c & 7) * 8;
        *(uint4*)&Qlds[r * 72 + e0] = *(const uint4*)&q_bf[((size_t)bh * 2048 + q0 + r) * 64 + e0];
    }
    __syncthreads();
    const int s0 = w * 16, s1 = 64 + w * 16;
    const int g0 = q0 + s0, g1 = q0 + s1;
    const int rmax0 = g0 + 15, rmax1 = g1 + 15;
    bf8_t aA0 = *(const bf8_t*)&Qlds[(s0 + ln) * 72 + quad * 8];
    bf8_t aA1 = *(const bf8_t*)&Qlds[(s0 + ln) * 72 + 32 + quad * 8];
    bf8_t aB0 = *(const bf8_t*)&Qlds[(s1 + ln) * 72 + quad * 8];
    bf8_t aB1 = *(const bf8_t*)&Qlds[(s1 + ln) * 72 + 32 + quad * 8];
    const unsigned short* kb_base = k_bf + (size_t)bh * 2048 * 64;

    // ---- pass 1: row sums ----
    f4_t l0v = {0.f, 0.f, 0.f, 0.f}, l1v = {0.f, 0.f, 0.f, 0.f};
    const f4_t zf = {0.f, 0.f, 0.f, 0.f};
    const int nkt = (rmax1 >> 4) + 1;
    for (int kt = 0; kt < nkt; ++kt) {
        int col0 = kt * 16, col = col0 + ln;
        const unsigned short* kp = kb_base + (size_t)(col0 + ln) * 64 + quad * 8;
        bf8_t b0 = *(const bf8_t*)kp;
        bf8_t b1 = *(const bf8_t*)(kp + 32);
        f4_t sc = MFMA(aB0, b0, zf); sc = MFMA(aB1, b1, sc);
#pragma unroll
        for (int v = 0; v < 4; ++v) {
            if (col <= g1 + quad * 4 + v) l1v[v] += __expf(sc[v]);
        }
        if (col0 <= rmax0) {
            f4_t sc0 = MFMA(aA0, b0, zf); sc0 = MFMA(aA1, b1, sc0);
#pragma unroll
            for (int v = 0; v < 4; ++v) {
                if (col <= g0 + quad * 4 + v) l0v[v] += __expf(sc0[v]);
            }
        }
    }
#pragma unroll
    for (int m = 1; m < 16; m <<= 1) {
#pragma unroll
        for (int v = 0; v < 4; ++v) {
            l0v[v] += __shfl_xor(l0v[v], m);
            l1v[v] += __shfl_xor(l1v[v], m);
        }
    }
    f4_t linv0, linv1;
#pragma unroll
    for (int v = 0; v < 4; ++v) { linv0[v] = 1.f / l0v[v]; linv1[v] = 1.f / l1v[v]; }

    // ---- pass 2 ----
    f4_t o0[4] = {}, o1[4] = {};
    float* awp = attn_w + (size_t)bh * 2048 * 2048;
    const unsigned short* vt_base = vT_bf + (size_t)bh * 64 * 2048;
    float* pw = &Pf32[w][0];
    for (int kc = 0; kc < 64; ++kc) {
        int col0c = kc * 32;
        bool act1 = col0c <= rmax1, act0 = col0c <= rmax0;
        bf8_t kf[4], vb[4];
        if (act1) {
#pragma unroll
            for (int sub = 0; sub < 2; ++sub) {
                const unsigned short* kp = kb_base + (size_t)(col0c + sub * 16 + ln) * 64 + quad * 8;
                kf[sub * 2] = *(const bf8_t*)kp;
                kf[sub * 2 + 1] = *(const bf8_t*)(kp + 32);
            }
#pragma unroll
            for (int j = 0; j < 4; ++j)
                vb[j] = *(const bf8_t*)(vt_base + (size_t)(j * 16 + ln) * 2048 + col0c + quad * 8);
        }
        auto do_strip = [&](int gb, bf8_t a0, bf8_t a1, const f4_t& linv, f4_t* oacc, bool active) {
            if (active) {
#pragma unroll
                for (int sub = 0; sub < 2; ++sub) {
                    f4_t sc = MFMA(a0, kf[sub * 2], zf);
                    sc = MFMA(a1, kf[sub * 2 + 1], sc);
                    int col = col0c + sub * 16 + ln;
#pragma unroll
                    for (int v = 0; v < 4; ++v) {
                        int row = gb + quad * 4 + v;
                        float p = (col <= row) ? __expf(sc[v]) * linv[v] : 0.f;
                        pw[(quad * 4 + v) * 36 + sub * 16 + ln] = p;
                    }
                }
                // coalesced 128B-row stores from LDS (intra-wave LDS is in-order)
#pragma unroll
                for (int half = 0; half < 2; ++half) {
                    int r = half * 8 + (lane >> 3), cq = lane & 7;
                    float4 val = *(const float4*)&pw[r * 36 + cq * 4];
                    *(float4*)&awp[(size_t)(gb + r) * 2048 + col0c + cq * 4] = val;
                }
                // PV: read P row back, pack to bf16 A-fragment
                float4 pa = *(const float4*)&pw[ln * 36 + quad * 8];
                float4 pb = *(const float4*)&pw[ln * 36 + quad * 8 + 4];
                bf8_t pf;
                pf[0] = (short)f2bf(pa.x); pf[1] = (short)f2bf(pa.y);
                pf[2] = (short)f2bf(pa.z); pf[3] = (short)f2bf(pa.w);
                pf[4] = (short)f2bf(pb.x); pf[5] = (short)f2bf(pb.y);
                pf[6] = (short)f2bf(pb.z); pf[7] = (short)f2bf(pb.w);
#pragma unroll
                for (int j = 0; j < 4; ++j) oacc[j] = MFMA(pf, vb[j], oacc[j]);
            } else {
                float4 z4 = {0.f, 0.f, 0.f, 0.f};
#pragma unroll
                for (int half = 0; half < 2; ++half) {
                    int r = half * 8 + (lane >> 3), cq = lane & 7;
                    *(float4*)&awp[(size_t)(gb + r) * 2048 + col0c + cq * 4] = z4;
                }
            }
        };
        do_strip(g1, aB0, aB1, linv1, o1, act1);
        do_strip(g0, aA0, aA1, linv0, o0, act0);
    }
    int b = bh >> 4, h = bh & 15;
#pragma unroll
    for (int j = 0; j < 4; ++j) {
#pragma unroll
        for (int v = 0; v < 4; ++v) {
            int e = h * 64 + j * 16 + ln;
            attnpre[(size_t)(b * 2048 + g0 + quad * 4 + v) * 1024 + e] = f2bf(o0[j][v]);
            attnpre[(size_t)(b * 2048 + g1 + quad * 4 + v) * 1024 + e] = f2bf(o1[j][v]);
        }
    }
}

// ---------------- launch ----------------
extern "C" void kernel_launch(void* const* d_in, const int* in_sizes, int n_in,
                              void* d_out, int out_size, void* d_ws, size_t ws_size,
                              hipStream_t stream)
{
    const float* hs = (const float*)d_in[0];
    const float* wq = (const float*)d_in[1];
    const float* bq = (const float*)d_in[2];
    const float* wk = (const float*)d_in[3];
    const float* bk = (const float*)d_in[4];
    const float* wv = (const float*)d_in[5];
    const float* bv = (const float*)d_in[6];
    const float* wc = (const float*)d_in[7];
    const float* bc = (const float*)d_in[8];

    float* out      = (float*)d_out;
    float* out_aw   = out + NE;
    float* out_k    = out_aw + AW;
    float* out_v    = out_k + NE;

    char* ws = (char*)d_ws;
    unsigned short* hid_bf  = (unsigned short*)(ws);                // 8 MB
    unsigned short* wqkvT   = (unsigned short*)(ws + 8388608);      // 6 MB
    unsigned short* wcT     = (unsigned short*)(ws + 14680064);     // 2 MB
    unsigned short* q_bf    = (unsigned short*)(ws + 16777216);     // 8 MB
    unsigned short* k_bf    = (unsigned short*)(ws + 25165824);     // 8 MB
    unsigned short* vT_bf   = (unsigned short*)(ws + 33554432);     // 8 MB
    unsigned short* attnpre = (unsigned short*)(ws + 41943040);     // 8 MB

    cast_hidden<<<4096, 256, 0, stream>>>(hs, hid_bf);
    transpose_w<<<dim3(32, 32, 4), dim3(32, 8), 0, stream>>>(wq, wk, wv, wc, wqkvT, wcT);
    gemm_qkv<<<dim3(24, 32), 256, 0, stream>>>(hid_bf, wqkvT, bq, bk, bv,
                                               q_bf, k_bf, vT_bf, out_k, out_v);
    attn_fused<<<dim3(32, 16), 256, 0, stream>>>(q_bf, k_bf, vT_bf, out_aw, attnpre);
    gemm_cproj<<<dim3(8, 32), 256, 0, stream>>>(attnpre, wcT, bc, out);
}